// Round 6
// baseline (731.274 us; speedup 1.0000x reference)
//
#include <hip/hip_runtime.h>

#define TSEQ 1024
#define HID_ 1024
#define NH 8
#define DK 128
#define DV 128
#define ROWS 2048               // B*T
#define SZf (ROWS * HID_)       // floats per [2048,1024] matrix

typedef __attribute__((ext_vector_type(8))) short short8;
typedef __attribute__((ext_vector_type(4))) float f32x4;

__device__ __forceinline__ float sig_(float x) { return 1.f / (1.f + __expf(-x)); }

__device__ __forceinline__ ushort f2bf(float f) {   // RNE f32->bf16
    unsigned int u = __builtin_bit_cast(unsigned int, f);
    u += 0x7FFF + ((u >> 16) & 1);
    return (ushort)(u >> 16);
}
__device__ __forceinline__ unsigned int pk2(float lo, float hi) {
    return (unsigned int)f2bf(lo) | ((unsigned int)f2bf(hi) << 16);
}

// ---- 8-lane butterfly reduce at VALU speed via DPP
template<int CTRL>
__device__ __forceinline__ float dpp_add(float x) {
    int yi = __builtin_amdgcn_update_dpp(0, __builtin_bit_cast(int, x),
                                         CTRL, 0xF, 0xF, true);
    return x + __builtin_bit_cast(float, yi);
}
__device__ __forceinline__ float reduce8_dpp(float x) {
    x = dpp_add<0xB1>(x);
    x = dpp_add<0x4E>(x);
    x = dpp_add<0x141>(x);
    return x;
}

// ---------------- weight transpose+convert: W f32 [K][N] -> WT bf16 [N][K] ----
__global__ __launch_bounds__(256)
void k_wT(const float* __restrict__ s0, const float* __restrict__ s1,
          const float* __restrict__ s2, const float* __restrict__ s3,
          ushort* __restrict__ dst)
{
    const int z = blockIdx.z;
    const float* W = (z == 0) ? s0 : (z == 1) ? s1 : (z == 2) ? s2 : s3;
    ushort* WT = dst + (size_t)z * (1024 * 1024);
    __shared__ float t[64][65];
    const int n0 = blockIdx.x * 64, k0 = blockIdx.y * 64;
    const int rr = threadIdx.x >> 4, cc = threadIdx.x & 15;
#pragma unroll
    for (int i = 0; i < 4; ++i) {
        const int row = i * 16 + rr;
        float4 v = *(const float4*)(W + (size_t)(k0 + row) * 1024 + n0 + cc * 4);
        t[row][cc * 4 + 0] = v.x; t[row][cc * 4 + 1] = v.y;
        t[row][cc * 4 + 2] = v.z; t[row][cc * 4 + 3] = v.w;
    }
    __syncthreads();
#pragma unroll
    for (int i = 0; i < 4; ++i) {
        const int n = i * 16 + rr;
        const int kc = cc * 4;
        ushort4 o;
        o.x = f2bf(t[kc + 0][n]); o.y = f2bf(t[kc + 1][n]);
        o.z = f2bf(t[kc + 2][n]); o.w = f2bf(t[kc + 3][n]);
        *(ushort4*)(WT + (size_t)(n0 + n) * 1024 + k0 + kc) = o;
    }
}

// ---------------- bf16 MFMA GEMM: C[M][1024] = A f32 [M][1024] x BT bf16 [N][K] ----
#define LDSB 40        // bf16 stride: 80B rows, 16B-aligned frags, <=2-way banks
__device__ __forceinline__ void gemm_tile_mfma(const float* __restrict__ A,
                                               const ushort* __restrict__ BT,
                                               float* __restrict__ C,
                                               int brow, int bcol)
{
    __shared__ ushort As[128 * LDSB];
    __shared__ ushort Bs[128 * LDSB];
    const int tid  = threadIdx.x;
    const int lane = tid & 63;
    const int wv   = tid >> 6;
    const int wm   = (wv >> 1) * 64;     // wave row offset
    const int wn   = (wv & 1) * 64;      // wave col offset
    const int l15  = lane & 15;
    const int k8   = (lane >> 4) * 8;    // frag k offset (bf16)
    const int srow = tid >> 1;           // staging row 0..127
    const int skh  = (tid & 1) * 16;     // staging k half

    f32x4 acc[4][4];
#pragma unroll
    for (int i = 0; i < 4; ++i)
#pragma unroll
        for (int j = 0; j < 4; ++j)
#pragma unroll
            for (int e = 0; e < 4; ++e) acc[i][j][e] = 0.f;

    const float*  arow = A  + (size_t)(brow + srow) * 1024 + skh;
    const ushort* brp  = BT + (size_t)(bcol + srow) * 1024 + skh;
    ushort* asw = As + srow * LDSB + skh;
    ushort* bsw = Bs + srow * LDSB + skh;

    for (int k0 = 0; k0 < 1024; k0 += 32) {
        float4 a0 = *(const float4*)(arow + k0);
        float4 a1 = *(const float4*)(arow + k0 + 4);
        float4 a2 = *(const float4*)(arow + k0 + 8);
        float4 a3 = *(const float4*)(arow + k0 + 12);
        uint4 b0 = *(const uint4*)(brp + k0);
        uint4 b1 = *(const uint4*)(brp + k0 + 8);
        uint4 w0, w1;
        w0.x = pk2(a0.x, a0.y); w0.y = pk2(a0.z, a0.w);
        w0.z = pk2(a1.x, a1.y); w0.w = pk2(a1.z, a1.w);
        w1.x = pk2(a2.x, a2.y); w1.y = pk2(a2.z, a2.w);
        w1.z = pk2(a3.x, a3.y); w1.w = pk2(a3.z, a3.w);
        __syncthreads();                 // prev iter's frag reads done
        *(uint4*)(asw)     = w0;
        *(uint4*)(asw + 8) = w1;
        *(uint4*)(bsw)     = b0;
        *(uint4*)(bsw + 8) = b1;
        __syncthreads();
        short8 af[4], bf[4];
#pragma unroll
        for (int i = 0; i < 4; ++i)
            af[i] = *(const short8*)(As + (wm + i * 16 + l15) * LDSB + k8);
#pragma unroll
        for (int j = 0; j < 4; ++j)
            bf[j] = *(const short8*)(Bs + (wn + j * 16 + l15) * LDSB + k8);
#pragma unroll
        for (int i = 0; i < 4; ++i)
#pragma unroll
            for (int j = 0; j < 4; ++j)
                acc[i][j] = __builtin_amdgcn_mfma_f32_16x16x32_bf16(
                    af[i], bf[j], acc[i][j], 0, 0, 0);
    }
    const int l4 = lane >> 4;
#pragma unroll
    for (int i = 0; i < 4; ++i)
#pragma unroll
        for (int j = 0; j < 4; ++j)
#pragma unroll
            for (int r = 0; r < 4; ++r)
                C[(size_t)(brow + wm + i * 16 + l4 * 4 + r) * 1024 +
                  bcol + wn + j * 16 + l15] = acc[i][j][r];
}

__global__ __launch_bounds__(256)
void k_gemm4(const float* __restrict__ A, const ushort* __restrict__ WT,
             float* __restrict__ Cbase)
{
    const ushort* BT = WT + (size_t)blockIdx.z * (1024 * 1024);
    float* C = Cbase + (size_t)blockIdx.z * SZf;
    gemm_tile_mfma(A, BT, C, blockIdx.y * 128, blockIdx.x * 128);
}

__global__ __launch_bounds__(256)
void k_gemm1(const float* __restrict__ A, const ushort* __restrict__ BT,
             float* __restrict__ C)
{
    gemm_tile_mfma(A, BT, C, blockIdx.y * 128, blockIdx.x * 128);
}

// -------- alpha/beta small GEMM + sigmoid; writes TRANSPOSED [bh][t] --------
__global__ __launch_bounds__(64)
void k_ab(const float* __restrict__ x, const float* __restrict__ Wa,
          const float* __restrict__ ba, const float* __restrict__ Wb,
          const float* __restrict__ bb, float* __restrict__ aT,
          float* __restrict__ bT)
{
    const int r = blockIdx.x;           // r = b*1024 + t
    const int lane = threadIdx.x;
    const int b = r >> 10, t = r & 1023;
    const float* xr = x + (size_t)r * HID_;
    float acc[16];
#pragma unroll
    for (int n = 0; n < 16; ++n) acc[n] = 0.f;
    for (int c = lane; c < HID_; c += 64) {
        const float xv = xr[c];
        const float* wa = Wa + c * 8;
        const float* wb = Wb + c * 8;
#pragma unroll
        for (int n = 0; n < 8; ++n) {
            acc[n]     = fmaf(xv, wa[n], acc[n]);
            acc[8 + n] = fmaf(xv, wb[n], acc[8 + n]);
        }
    }
#pragma unroll
    for (int n = 0; n < 16; ++n) {
#pragma unroll
        for (int m = 32; m; m >>= 1) acc[n] += __shfl_xor(acc[n], m);
    }
    if (lane < 8) {
        aT[(size_t)(b * 8 + lane) * TSEQ + t] = sig_(acc[lane] + ba[lane]);
        bT[(size_t)(b * 8 + lane) * TSEQ + t] = sig_(acc[8 + lane] + bb[lane]);
    }
}

// -------- causal depthwise conv K=4 + SiLU (+scale), in-place, T-parallel ----
__global__ __launch_bounds__(256)
void k_conv_save(const float* __restrict__ q, const float* __restrict__ k,
                 const float* __restrict__ v, float* __restrict__ scr)
{
    const int z = blockIdx.z, b = blockIdx.y, j = blockIdx.x + 1;  // j=1..15
    const float* y = (z == 0) ? q : (z == 1) ? k : v;
    float* d = scr + ((size_t)(z * 2 + b) * 15 + (j - 1)) * 3 * 1024;
    const float* s = y + ((size_t)b * TSEQ + j * 64 - 3) * HID_;
    for (int i = threadIdx.x; i < 3 * 1024; i += 256)
        d[i] = s[i];
}

__global__ __launch_bounds__(256)
void k_conv_apply(float* __restrict__ q, float* __restrict__ k, float* __restrict__ v,
                  const float* __restrict__ scr,
                  const float* __restrict__ wq, const float* __restrict__ bq,
                  const float* __restrict__ wk, const float* __restrict__ bk,
                  const float* __restrict__ wv, const float* __restrict__ bv)
{
    const int z = blockIdx.z, b = blockIdx.y;
    const int j = blockIdx.x >> 2, cg = blockIdx.x & 3;
    float* y          = (z == 0) ? q  : (z == 1) ? k  : v;
    const float* w    = (z == 0) ? wq : (z == 1) ? wk : wv;
    const float* bias = (z == 0) ? bq : (z == 1) ? bk : bv;
    const float scale = (z == 1) ? 0.08838834764831845f : 1.f;  // Dk^-0.5 on k
    const int c = cg * 256 + threadIdx.x;
    const float w0 = w[c * 4], w1 = w[c * 4 + 1], w2 = w[c * 4 + 2], w3 = w[c * 4 + 3];
    const float bs = bias[c];
    float y0 = 0.f, y1 = 0.f, y2 = 0.f;
    if (j > 0) {
        const float* s = scr + ((size_t)(z * 2 + b) * 15 + (j - 1)) * 3 * 1024 + c;
        y0 = s[0]; y1 = s[1024]; y2 = s[2048];
    }
    float* yp = y + ((size_t)b * TSEQ + j * 64) * HID_ + c;
#pragma unroll 4
    for (int t = 0; t < 64; ++t) {
        float y3  = yp[(size_t)t * HID_];
        float acc = fmaf(w0, y0, fmaf(w1, y1, fmaf(w2, y2, fmaf(w3, y3, bs))));
        float sv  = acc * sig_(acc) * scale;
        yp[(size_t)t * HID_] = sv;
        y0 = y1; y1 = y2; y2 = y3;
    }
}

// ------------- chunked WY scan: parallel dots + scalar forward-sub -----------
// Per chunk of L=16:  u_t = S0.k_t, u'_t = S0.q_t (parallel dots),
// Ecoef[t][s] = D[s+1,t-1]*(k_s.k_t), Oc[t][s] = D[s+1,t]*(k_s.q_t)  (256 pairs
// = 256 threads), then per-row forward substitution (3-op chain per step):
//   w_t = b_t*(v_t - (D[0,t-1]*u_t + sum_{s<t} Ecoef[t][s]*w_s))
//   o_t = D[0,t]*u'_t + sum_{s<=t} Oc[t][s]*w_s
//   S  <- D[0,15]*S + sum_s D[s+1,15]*w_s k_s^T
// All decay coefs are products of sigmoids in (0,1] -> stable, no divisions.
#define SCH 16
#define NCH (TSEQ / SCH)
#define NF4 1160                 // float4s per chunk: K 512 | Q 512 | V 128 | A 4 | B 4
#define QOFF 2048
#define VOFF 4096
#define AOFF 4608
#define BOFF 4624
#define CBUF 4640

__global__ __launch_bounds__(256)
void k_scan(const float* __restrict__ qlin, const float* __restrict__ klin,
            const float* __restrict__ vlin, const float* __restrict__ aT,
            const float* __restrict__ bT, float* __restrict__ o)
{
    const int bh  = blockIdx.x >> 2;
    const int rb  = blockIdx.x & 3;
    const int b   = bh >> 3;
    const int h   = bh & 7;
    const int tid = threadIdx.x;
    const int row = tid >> 3;
    const int oct = tid & 7;

    const float* kbase = klin + (size_t)b * TSEQ * HID_ + h * DK;
    const float* qbase = qlin + (size_t)b * TSEQ * HID_ + h * DK;
    const float* vbase = vlin + (size_t)b * TSEQ * HID_ + h * DV + rb * 32;
    const float* ap = aT + (size_t)bh * TSEQ;
    const float* bp = bT + (size_t)bh * TSEQ;

    __shared__ float chunk[2][CBUF];
    __shared__ float Ecoef[16][16];   // [t][s], valid s<t
    __shared__ float Ocoef[16][16];   // [t][s], valid s<=t

    // staging descriptors (identical to verified R5 machinery)
    const float* srcp[5];
    int strd[5], dof[5];
    bool val[5];
#pragma unroll
    for (int j = 0; j < 5; ++j) {
        const int i4 = j * 256 + tid;
        val[j] = (i4 < NF4);
        const float* s = kbase; int st = 0; int d = i4;
        if (i4 < 512) {
            const int t = i4 >> 5, c4 = i4 & 31, os = c4 >> 2, ql = c4 & 3;
            s = kbase + (size_t)t * HID_ + (c4 << 2); st = SCH * HID_;
            d = t * 32 + os * 4 + ((ql + (os >> 1)) & 3);            // swizzled
        } else if (i4 < 1024) {
            const int m = i4 - 512;
            const int t = m >> 5, c4 = m & 31, os = c4 >> 2, ql = c4 & 3;
            s = qbase + (size_t)t * HID_ + (c4 << 2); st = SCH * HID_;
            d = 512 + t * 32 + os * 4 + ((ql + (os >> 1)) & 3);      // swizzled
        } else if (i4 < 1152) {
            const int m = i4 - 1024;
            s = vbase + (size_t)(m >> 3) * HID_ + ((m & 7) << 2); st = SCH * HID_;
        } else if (i4 < 1156) {
            s = ap + ((i4 - 1152) << 2); st = SCH;
        } else {
            s = bp + ((i4 - 1156) << 2); st = SCH;
        }
        srcp[j] = s; strd[j] = st; dof[j] = d * 4;
    }

    // gram pair decode: tids 0..119 -> (s<t) K.K pairs; 120..255 -> (s<=t) K.Q
    int gs, gt;
    const bool isFG = (tid >= 120);
    if (!isFG) {
        const int t = (int)((1.f + sqrtf(1.f + 8.f * (float)tid)) * 0.5f);
        gs = tid - (t * (t - 1)) / 2; gt = t;
    } else {
        const int e = tid - 120;
        const int t = (int)((sqrtf(8.f * (float)e + 1.f) - 1.f) * 0.5f);
        gs = e - (t * (t + 1)) / 2; gt = t;
    }
    const int glim = isFG ? gt : (gt - 1);   // decay factors j in (gs, glim]

    float S[16];
#pragma unroll
    for (int i = 0; i < 16; ++i) S[i] = 0.f;

    float r[20];
#pragma unroll
    for (int j = 0; j < 5; ++j)
        if (val[j]) *(float4*)(&r[j * 4]) = *(const float4*)(srcp[j]);
#pragma unroll
    for (int j = 0; j < 5; ++j)
        if (val[j]) *(float4*)(&chunk[0][dof[j]]) = *(const float4*)(&r[j * 4]);
    __syncthreads();

    float* optr = o + (size_t)bh * TSEQ * DV + rb * 32 + row;
    const int swz = oct >> 1;
    const int ln = tid & 63;

    for (int c = 0; c < NCH; ++c) {
        const int cur = c & 1;
        if (c + 1 < NCH) {      // issue next chunk's loads; held in regs thru compute
#pragma unroll
            for (int j = 0; j < 5; ++j)
                if (val[j]) *(float4*)(&r[j * 4]) =
                    *(const float4*)(srcp[j] + (size_t)(c + 1) * strd[j]);
        }
        const float* cb = chunk[cur];
        const float* p0 = cb + oct * 16 + (((0 + swz) & 3) << 2);
        const float* p1 = cb + oct * 16 + (((1 + swz) & 3) << 2);
        const float* p2 = cb + oct * 16 + (((2 + swz) & 3) << 2);
        const float* p3 = cb + oct * 16 + (((3 + swz) & 3) << 2);
        const int t0 = c * SCH;

        // ---- phase B: u_t = S0.k_t, up_t = S0.q_t (16 parallel dots each)
        float u[16], up[16];
#pragma unroll
        for (int t = 0; t < SCH; ++t) {
            const float4 k0 = *(const float4*)(p0 + t * 128);
            const float4 k1 = *(const float4*)(p1 + t * 128);
            const float4 k2 = *(const float4*)(p2 + t * 128);
            const float4 k3 = *(const float4*)(p3 + t * 128);
            float a0 = fmaf(S[0],  k0.x, fmaf(S[1],  k0.y, fmaf(S[2],  k0.z, S[3]  * k0.w)));
            float a1 = fmaf(S[4],  k1.x, fmaf(S[5],  k1.y, fmaf(S[6],  k1.z, S[7]  * k1.w)));
            float a2 = fmaf(S[8],  k2.x, fmaf(S[9],  k2.y, fmaf(S[10], k2.z, S[11] * k2.w)));
            float a3 = fmaf(S[12], k3.x, fmaf(S[13], k3.y, fmaf(S[14], k3.z, S[15] * k3.w)));
            u[t] = reduce8_dpp((a0 + a1) + (a2 + a3));
        }
#pragma unroll
        for (int t = 0; t < SCH; ++t) {
            const float4 q0 = *(const float4*)(p0 + QOFF + t * 128);
            const float4 q1 = *(const float4*)(p1 + QOFF + t * 128);
            const float4 q2 = *(const float4*)(p2 + QOFF + t * 128);
            const float4 q3 = *(const float4*)(p3 + QOFF + t * 128);
            float a0 = fmaf(S[0],  q0.x, fmaf(S[1],  q0.y, fmaf(S[2],  q0.z, S[3]  * q0.w)));
            float a1 = fmaf(S[4],  q1.x, fmaf(S[5],  q1.y, fmaf(S[6],  q1.z, S[7]  * q1.w)));
            float a2 = fmaf(S[8],  q2.x, fmaf(S[9],  q2.y, fmaf(S[10], q2.z, S[11] * q2.w)));
            float a3 = fmaf(S[12], q3.x, fmaf(S[13], q3.y, fmaf(S[14], q3.z, S[15] * q3.w)));
            up[t] = reduce8_dpp((a0 + a1) + (a2 + a3));
        }

        // ---- phase C: gram + decay fold (1 pair per thread; swizzle cancels
        // in dots; lane-rotated scalar reads -> 2-way banks = free)
        {
            const float* ra = cb + gs * 128;                       // K_gs
            const float* rb2 = cb + (isFG ? QOFF : 0) + gt * 128;  // K_gt / Q_gt
            float g0 = 0.f, g1 = 0.f, g2 = 0.f, g3 = 0.f;
#pragma unroll
            for (int i = 0; i < 128; i += 4) {
                const int d0 = (i + 0 + ln) & 127;
                const int d1 = (i + 1 + ln) & 127;
                const int d2 = (i + 2 + ln) & 127;
                const int d3 = (i + 3 + ln) & 127;
                g0 = fmaf(ra[d0], rb2[d0], g0);
                g1 = fmaf(ra[d1], rb2[d1], g1);
                g2 = fmaf(ra[d2], rb2[d2], g2);
                g3 = fmaf(ra[d3], rb2[d3], g3);
            }
            float gg = (g0 + g1) + (g2 + g3);
            float rp = 1.f;
#pragma unroll
            for (int j = 1; j < 16; ++j) {
                const float aj = cb[AOFF + j];
                rp *= (j > gs && j <= glim) ? aj : 1.f;
            }
            if (!isFG) Ecoef[gt][gs] = rp * gg;
            else       Ocoef[gt][gs] = rp * gg;
        }
        __syncthreads();

        // ---- phase E: forward substitution (per-row; short scalar chain)
        float w[16], acc[16];
#pragma unroll
        for (int i = 0; i < 16; ++i) acc[i] = 0.f;
        float pu = 1.f;                       // D[0,t-1]
#pragma unroll
        for (int t = 0; t < SCH; ++t) {
            const float bt = cb[BOFF + t];
            const float vt = cb[VOFF + t * 32 + row];
            const float sk = fmaf(pu, u[t], acc[t]);
            const float wt = bt * (vt - sk);
            w[t] = wt;
#pragma unroll
            for (int t2 = t + 1; t2 < SCH; ++t2)
                acc[t2] = fmaf(Ecoef[t2][t], wt, acc[t2]);
            pu *= cb[AOFF + t];
        }
        // pu = D[0,15]

        // ---- phase F: outputs (redundant across octs; oct0 stores)
        {
            float po = 1.f;
#pragma unroll
            for (int t = 0; t < SCH; ++t) {
                po *= cb[AOFF + t];           // D[0,t]
                float ov = po * up[t];
#pragma unroll
                for (int s = 0; s <= t; ++s)
                    ov = fmaf(Ocoef[t][s], w[s], ov);
                if (oct == 0) optr[(size_t)(t0 + t) * DV] = ov;
            }
        }

        // ---- phase G: state update  S = D[0,15]*S + sum_s D[s+1,15]*w_s k_s^T
        {
#pragma unroll
            for (int i = 0; i < 16; ++i) S[i] *= pu;
            float sc = 1.f;                   // D[s+1,15]
#pragma unroll
            for (int s = SCH - 1; s >= 0; --s) {
                const float ws = sc * w[s];
                const float4 k0 = *(const float4*)(p0 + s * 128);
                const float4 k1 = *(const float4*)(p1 + s * 128);
                const float4 k2 = *(const float4*)(p2 + s * 128);
                const float4 k3 = *(const float4*)(p3 + s * 128);
                S[0]  = fmaf(ws, k0.x, S[0]);
                S[1]  = fmaf(ws, k0.y, S[1]);
                S[2]  = fmaf(ws, k0.z, S[2]);
                S[3]  = fmaf(ws, k0.w, S[3]);
                S[4]  = fmaf(ws, k1.x, S[4]);
                S[5]  = fmaf(ws, k1.y, S[5]);
                S[6]  = fmaf(ws, k1.z, S[6]);
                S[7]  = fmaf(ws, k1.w, S[7]);
                S[8]  = fmaf(ws, k2.x, S[8]);
                S[9]  = fmaf(ws, k2.y, S[9]);
                S[10] = fmaf(ws, k2.z, S[10]);
                S[11] = fmaf(ws, k2.w, S[11]);
                S[12] = fmaf(ws, k3.x, S[12]);
                S[13] = fmaf(ws, k3.y, S[13]);
                S[14] = fmaf(ws, k3.z, S[14]);
                S[15] = fmaf(ws, k3.w, S[15]);
                sc *= cb[AOFF + s];
            }
        }

        if (c + 1 < NCH) {      // land next chunk into the other buffer
            float* wbf = (float*)chunk[cur ^ 1];
#pragma unroll
            for (int j = 0; j < 5; ++j)
                if (val[j]) *(float4*)(wbf + dof[j]) = *(const float4*)(&r[j * 4]);
        }
        __syncthreads();
    }
}

// ---------------- LayerNorm(Dv) + sigmoid gate ----------------
__global__ __launch_bounds__(256)
void k_ln_gate(const float* __restrict__ o, const float* __restrict__ g_lin,
               const float* __restrict__ ln_g, const float* __restrict__ ln_b,
               float* __restrict__ og)
{
    const int idx  = blockIdx.x * 4 + (threadIdx.x >> 6);
    const int lane = threadIdx.x & 63;
    const int h  = idx & 7;
    const int bt = idx >> 3;
    const int b  = bt >> 10;
    const int t  = bt & 1023;
    const float* op = o + ((size_t)(b * NH + h) * TSEQ + t) * DV;
    float2 xv = ((const float2*)op)[lane];
    float s = xv.x + xv.y;
#pragma unroll
    for (int m = 32; m; m >>= 1) s += __shfl_xor(s, m);
    const float mu = s * (1.f / 128.f);
    const float d0 = xv.x - mu, d1 = xv.y - mu;
    float v = d0 * d0 + d1 * d1;
#pragma unroll
    for (int m = 32; m; m >>= 1) v += __shfl_xor(v, m);
    const float inv = rsqrtf(v * (1.f / 128.f) + 1e-5f);
    const int d = lane * 2;
    const float* gp = g_lin + (size_t)bt * HID_ + h * DV;
    const float g0 = sig_(gp[d]), g1 = sig_(gp[d + 1]);
    const float y0 = (d0 * inv * ln_g[d]     + ln_b[d])     * g0;
    const float y1 = (d1 * inv * ln_g[d + 1] + ln_b[d + 1]) * g1;
    ((float2*)(og + (size_t)bt * HID_ + h * DV))[lane] = make_float2(y0, y1);
}

extern "C" void kernel_launch(void* const* d_in, const int* in_sizes, int n_in,
                              void* d_out, int out_size, void* d_ws, size_t ws_size,
                              hipStream_t stream)
{
    const float* x   = (const float*)d_in[0];
    const float* Wq  = (const float*)d_in[1];
    const float* Wk  = (const float*)d_in[2];
    const float* Wv  = (const float*)d_in[3];
    const float* cqw = (const float*)d_in[4];
    const float* cqb = (const float*)d_in[5];
    const float* ckw = (const float*)d_in[6];
    const float* ckb = (const float*)d_in[7];
    const float* cvw = (const float*)d_in[8];
    const float* cvb = (const float*)d_in[9];
    const float* Wa  = (const float*)d_in[10];
    const float* ba  = (const float*)d_in[11];
    const float* Wb  = (const float*)d_in[12];
    const float* bb  = (const float*)d_in[13];
    const float* Wg  = (const float*)d_in[14];
    const float* Wo  = (const float*)d_in[15];
    const float* lng = (const float*)d_in[16];
    const float* lnb = (const float*)d_in[17];
    float* out = (float*)d_out;
    float* ws  = (float*)d_ws;

    float* q_lin = ws;                       // gemm out -> conv'd in place -> og
    float* k_lin = ws + 1 * (size_t)SZf;     //              -> WoT (after scan)
    float* v_lin = ws + 2 * (size_t)SZf;
    float* g_lin = ws + 3 * (size_t)SZf;
    float* o_buf = ws + 4 * (size_t)SZf;     // WT4 -> conv scratch -> scan out
    float* aT    = ws + 5 * (size_t)SZf;
    float* bT    = aT + 16 * TSEQ;
    float* og    = ws;

    ushort* WT4 = (ushort*)o_buf;            // 4 x 1M bf16 = 8MB, dead after gemm4
    ushort* WoT = (ushort*)k_lin;            // written after scan, dead after gemm1

    k_wT<<<dim3(16, 16, 4), 256, 0, stream>>>(Wq, Wk, Wv, Wg, WT4);
    k_gemm4<<<dim3(8, 16, 4), 256, 0, stream>>>(x, WT4, ws);
    k_ab<<<ROWS, 64, 0, stream>>>(x, Wa, ba, Wb, bb, aT, bT);
    k_conv_save<<<dim3(15, 2, 3), 256, 0, stream>>>(q_lin, k_lin, v_lin, o_buf);
    k_conv_apply<<<dim3(64, 2, 3), 256, 0, stream>>>(q_lin, k_lin, v_lin, o_buf,
                                                     cqw, cqb, ckw, ckb, cvw, cvb);
    k_scan<<<64, 256, 0, stream>>>(q_lin, k_lin, v_lin, aT, bT, o_buf);
    k_wT<<<dim3(16, 16, 1), 256, 0, stream>>>(Wo, Wo, Wo, Wo, WoT);
    k_ln_gate<<<4096, 256, 0, stream>>>(o_buf, g_lin, lng, lnb, og);
    k_gemm1<<<dim3(8, 16), 256, 0, stream>>>(og, WoT, out);
}

// Round 7
// 249.292 us; speedup vs baseline: 2.9334x; 2.9334x over previous
//
#include <hip/hip_runtime.h>

#define TSEQ 1024
#define HID_ 1024
#define NH 8
#define DK 128
#define DV 128
#define ROWS 2048               // B*T
#define SZf (ROWS * HID_)       // floats per [2048,1024] matrix
#define LCH 64                  // scan chunk length
#define NCK 16                  // chunks per (b,h)
#define KSTR 136                // bf16 LDS stride for [64][128] tiles
#define ESTR 65

typedef __attribute__((ext_vector_type(8))) short short8;
typedef __attribute__((ext_vector_type(4))) float f32x4;
#define MFMA __builtin_amdgcn_mfma_f32_16x16x32_bf16

__device__ __forceinline__ float sig_(float x) { return 1.f / (1.f + __expf(-x)); }

__device__ __forceinline__ ushort f2bf(float f) {   // RNE f32->bf16
    unsigned int u = __builtin_bit_cast(unsigned int, f);
    u += 0x7FFF + ((u >> 16) & 1);
    return (ushort)(u >> 16);
}
__device__ __forceinline__ unsigned int pk2(float lo, float hi) {
    return (unsigned int)f2bf(lo) | ((unsigned int)f2bf(hi) << 16);
}

// ---------------- weight transpose+convert: W f32 [K][N] -> WT bf16 [N][K] ----
__global__ __launch_bounds__(256)
void k_wT(const float* __restrict__ s0, const float* __restrict__ s1,
          const float* __restrict__ s2, const float* __restrict__ s3,
          ushort* __restrict__ dst)
{
    const int z = blockIdx.z;
    const float* W = (z == 0) ? s0 : (z == 1) ? s1 : (z == 2) ? s2 : s3;
    ushort* WT = dst + (size_t)z * (1024 * 1024);
    __shared__ float t[64][65];
    const int n0 = blockIdx.x * 64, k0 = blockIdx.y * 64;
    const int rr = threadIdx.x >> 4, cc = threadIdx.x & 15;
#pragma unroll
    for (int i = 0; i < 4; ++i) {
        const int row = i * 16 + rr;
        float4 v = *(const float4*)(W + (size_t)(k0 + row) * 1024 + n0 + cc * 4);
        t[row][cc * 4 + 0] = v.x; t[row][cc * 4 + 1] = v.y;
        t[row][cc * 4 + 2] = v.z; t[row][cc * 4 + 3] = v.w;
    }
    __syncthreads();
#pragma unroll
    for (int i = 0; i < 4; ++i) {
        const int n = i * 16 + rr;
        const int kc = cc * 4;
        ushort4 o;
        o.x = f2bf(t[kc + 0][n]); o.y = f2bf(t[kc + 1][n]);
        o.z = f2bf(t[kc + 2][n]); o.w = f2bf(t[kc + 3][n]);
        *(ushort4*)(WT + (size_t)(n0 + n) * 1024 + k0 + kc) = o;
    }
}

// ---------------- bf16 MFMA GEMM (verified R5) ----------------
#define LDSB 40
__device__ __forceinline__ void gemm_tile_mfma(const float* __restrict__ A,
                                               const ushort* __restrict__ BT,
                                               float* __restrict__ C,
                                               int brow, int bcol)
{
    __shared__ ushort As[128 * LDSB];
    __shared__ ushort Bs[128 * LDSB];
    const int tid  = threadIdx.x;
    const int lane = tid & 63;
    const int wv   = tid >> 6;
    const int wm   = (wv >> 1) * 64;
    const int wn   = (wv & 1) * 64;
    const int l15  = lane & 15;
    const int k8   = (lane >> 4) * 8;
    const int srow = tid >> 1;
    const int skh  = (tid & 1) * 16;

    f32x4 acc[4][4];
#pragma unroll
    for (int i = 0; i < 4; ++i)
#pragma unroll
        for (int j = 0; j < 4; ++j)
#pragma unroll
            for (int e = 0; e < 4; ++e) acc[i][j][e] = 0.f;

    const float*  arow = A  + (size_t)(brow + srow) * 1024 + skh;
    const ushort* brp  = BT + (size_t)(bcol + srow) * 1024 + skh;
    ushort* asw = As + srow * LDSB + skh;
    ushort* bsw = Bs + srow * LDSB + skh;

    for (int k0 = 0; k0 < 1024; k0 += 32) {
        float4 a0 = *(const float4*)(arow + k0);
        float4 a1 = *(const float4*)(arow + k0 + 4);
        float4 a2 = *(const float4*)(arow + k0 + 8);
        float4 a3 = *(const float4*)(arow + k0 + 12);
        uint4 b0 = *(const uint4*)(brp + k0);
        uint4 b1 = *(const uint4*)(brp + k0 + 8);
        uint4 w0, w1;
        w0.x = pk2(a0.x, a0.y); w0.y = pk2(a0.z, a0.w);
        w0.z = pk2(a1.x, a1.y); w0.w = pk2(a1.z, a1.w);
        w1.x = pk2(a2.x, a2.y); w1.y = pk2(a2.z, a2.w);
        w1.z = pk2(a3.x, a3.y); w1.w = pk2(a3.z, a3.w);
        __syncthreads();
        *(uint4*)(asw)     = w0;
        *(uint4*)(asw + 8) = w1;
        *(uint4*)(bsw)     = b0;
        *(uint4*)(bsw + 8) = b1;
        __syncthreads();
        short8 af[4], bf[4];
#pragma unroll
        for (int i = 0; i < 4; ++i)
            af[i] = *(const short8*)(As + (wm + i * 16 + l15) * LDSB + k8);
#pragma unroll
        for (int j = 0; j < 4; ++j)
            bf[j] = *(const short8*)(Bs + (wn + j * 16 + l15) * LDSB + k8);
#pragma unroll
        for (int i = 0; i < 4; ++i)
#pragma unroll
            for (int j = 0; j < 4; ++j)
                acc[i][j] = MFMA(af[i], bf[j], acc[i][j], 0, 0, 0);
    }
    const int l4 = lane >> 4;
#pragma unroll
    for (int i = 0; i < 4; ++i)
#pragma unroll
        for (int j = 0; j < 4; ++j)
#pragma unroll
            for (int r = 0; r < 4; ++r)
                C[(size_t)(brow + wm + i * 16 + l4 * 4 + r) * 1024 +
                  bcol + wn + j * 16 + l15] = acc[i][j][r];
}

__global__ __launch_bounds__(256)
void k_gemm4(const float* __restrict__ A, const ushort* __restrict__ WT,
             float* __restrict__ Cbase)
{
    const ushort* BT = WT + (size_t)blockIdx.z * (1024 * 1024);
    float* C = Cbase + (size_t)blockIdx.z * SZf;
    gemm_tile_mfma(A, BT, C, blockIdx.y * 128, blockIdx.x * 128);
}

__global__ __launch_bounds__(256)
void k_gemm1(const float* __restrict__ A, const ushort* __restrict__ BT,
             float* __restrict__ C)
{
    gemm_tile_mfma(A, BT, C, blockIdx.y * 128, blockIdx.x * 128);
}

// -------- alpha/beta small GEMM + sigmoid; writes TRANSPOSED [bh][t] --------
__global__ __launch_bounds__(64)
void k_ab(const float* __restrict__ x, const float* __restrict__ Wa,
          const float* __restrict__ ba, const float* __restrict__ Wb,
          const float* __restrict__ bb, float* __restrict__ aT,
          float* __restrict__ bT)
{
    const int r = blockIdx.x;
    const int lane = threadIdx.x;
    const int b = r >> 10, t = r & 1023;
    const float* xr = x + (size_t)r * HID_;
    float acc[16];
#pragma unroll
    for (int n = 0; n < 16; ++n) acc[n] = 0.f;
    for (int c = lane; c < HID_; c += 64) {
        const float xv = xr[c];
        const float* wa = Wa + c * 8;
        const float* wb = Wb + c * 8;
#pragma unroll
        for (int n = 0; n < 8; ++n) {
            acc[n]     = fmaf(xv, wa[n], acc[n]);
            acc[8 + n] = fmaf(xv, wb[n], acc[8 + n]);
        }
    }
#pragma unroll
    for (int n = 0; n < 16; ++n) {
#pragma unroll
        for (int m = 32; m; m >>= 1) acc[n] += __shfl_xor(acc[n], m);
    }
    if (lane < 8) {
        aT[(size_t)(b * 8 + lane) * TSEQ + t] = sig_(acc[lane] + ba[lane]);
        bT[(size_t)(b * 8 + lane) * TSEQ + t] = sig_(acc[8 + lane] + bb[lane]);
    }
}

// -------- causal depthwise conv K=4 + SiLU (+scale), in-place, T-parallel ----
__global__ __launch_bounds__(256)
void k_conv_save(const float* __restrict__ q, const float* __restrict__ k,
                 const float* __restrict__ v, float* __restrict__ scr)
{
    const int z = blockIdx.z, b = blockIdx.y, j = blockIdx.x + 1;
    const float* y = (z == 0) ? q : (z == 1) ? k : v;
    float* d = scr + ((size_t)(z * 2 + b) * 15 + (j - 1)) * 3 * 1024;
    const float* s = y + ((size_t)b * TSEQ + j * 64 - 3) * HID_;
    for (int i = threadIdx.x; i < 3 * 1024; i += 256)
        d[i] = s[i];
}

__global__ __launch_bounds__(256)
void k_conv_apply(float* __restrict__ q, float* __restrict__ k, float* __restrict__ v,
                  const float* __restrict__ scr,
                  const float* __restrict__ wq, const float* __restrict__ bq,
                  const float* __restrict__ wk, const float* __restrict__ bk,
                  const float* __restrict__ wv, const float* __restrict__ bv)
{
    const int z = blockIdx.z, b = blockIdx.y;
    const int j = blockIdx.x >> 2, cg = blockIdx.x & 3;
    float* y          = (z == 0) ? q  : (z == 1) ? k  : v;
    const float* w    = (z == 0) ? wq : (z == 1) ? wk : wv;
    const float* bias = (z == 0) ? bq : (z == 1) ? bk : bv;
    const float scale = (z == 1) ? 0.08838834764831845f : 1.f;
    const int c = cg * 256 + threadIdx.x;
    const float w0 = w[c * 4], w1 = w[c * 4 + 1], w2 = w[c * 4 + 2], w3 = w[c * 4 + 3];
    const float bs = bias[c];
    float y0 = 0.f, y1 = 0.f, y2 = 0.f;
    if (j > 0) {
        const float* s = scr + ((size_t)(z * 2 + b) * 15 + (j - 1)) * 3 * 1024 + c;
        y0 = s[0]; y1 = s[1024]; y2 = s[2048];
    }
    float* yp = y + ((size_t)b * TSEQ + j * 64) * HID_ + c;
#pragma unroll 4
    for (int t = 0; t < 64; ++t) {
        float y3  = yp[(size_t)t * HID_];
        float acc = fmaf(w0, y0, fmaf(w1, y1, fmaf(w2, y2, fmaf(w3, y3, bs))));
        float sv  = acc * sig_(acc) * scale;
        yp[(size_t)t * HID_] = sv;
        y0 = y1; y1 = y2; y2 = y3;
    }
}

// ============ chunked delta-rule, kernel P: per-chunk parallel precompute ====
// Per chunk (64 steps): grams KK/KQ (bf16 MFMA), decay folds (log-space),
// M = (I + diag(b) E)^-1 diag(b) via per-column forward substitution.
__global__ __launch_bounds__(256)
void k_prep(const float* __restrict__ klin, const float* __restrict__ qlin,
            const float* __restrict__ aT, const float* __restrict__ bT,
            ushort* __restrict__ Mg, ushort* __restrict__ Gg,
            float* __restrict__ pug, float* __restrict__ pog,
            float* __restrict__ cg, float* __restrict__ dtotg)
{
    const int cid = blockIdx.x;          // 0..255 = bh*16 + c
    const int bh = cid >> 4, c = cid & 15;
    const int b = bh >> 3, h = bh & 7;
    const int tid = threadIdx.x;
    const int t0 = c * LCH;

    __shared__ ushort Kb[64 * KSTR], Qb[64 * KSTR];
    __shared__ float Ef[64 * ESTR];
    __shared__ float Mf[64 * ESTR];
    __shared__ float cums[64], bv[64];

    if (tid < 64) {
        const float a = aT[(size_t)bh * TSEQ + t0 + tid];
        bv[tid] = bT[(size_t)bh * TSEQ + t0 + tid];
        float cs = __logf(a);
#pragma unroll
        for (int d = 1; d < 64; d <<= 1) {
            float pv = __shfl_up(cs, d);
            if (tid >= d) cs += pv;
        }
        cums[tid] = cs;
    }
    const float* kb = klin + ((size_t)b * TSEQ + t0) * HID_ + h * DK;
    const float* qb = qlin + ((size_t)b * TSEQ + t0) * HID_ + h * DK;
#pragma unroll
    for (int j = 0; j < 8; ++j) {
        const int i4 = tid + j * 256;
        const int row = i4 >> 5, c4 = i4 & 31;
        float4 kv = *(const float4*)(kb + (size_t)row * HID_ + c4 * 4);
        float4 qv = *(const float4*)(qb + (size_t)row * HID_ + c4 * 4);
        uint2 kp; kp.x = pk2(kv.x, kv.y); kp.y = pk2(kv.z, kv.w);
        uint2 qp; qp.x = pk2(qv.x, qv.y); qp.y = pk2(qv.z, qv.w);
        *(uint2*)(Kb + row * KSTR + c4 * 4) = kp;
        *(uint2*)(Qb + row * KSTR + c4 * 4) = qp;
    }
    __syncthreads();

    // grams: wave w owns t-tile row w; s-tiles 0..3
    const int wv = tid >> 6, l = tid & 63, l15 = l & 15, lq = l >> 4;
    const int k8o = lq * 8;
    f32x4 accK[4], accQ4[4];
#pragma unroll
    for (int j = 0; j < 4; ++j) {
        accK[j] = f32x4{0.f, 0.f, 0.f, 0.f};
        accQ4[j] = f32x4{0.f, 0.f, 0.f, 0.f};
    }
#pragma unroll
    for (int kk = 0; kk < 4; ++kk) {
        short8 aK = *(const short8*)(Kb + (wv * 16 + l15) * KSTR + kk * 32 + k8o);
        short8 aQ = *(const short8*)(Qb + (wv * 16 + l15) * KSTR + kk * 32 + k8o);
#pragma unroll
        for (int js = 0; js < 4; ++js) {
            short8 bK = *(const short8*)(Kb + (js * 16 + l15) * KSTR + kk * 32 + k8o);
            accK[js]  = MFMA(aK, bK, accK[js], 0, 0, 0);
            accQ4[js] = MFMA(aQ, bK, accQ4[js], 0, 0, 0);
        }
    }
    ushort* Gc = Gg + (size_t)cid * 4096;
#pragma unroll
    for (int js = 0; js < 4; ++js) {
#pragma unroll
        for (int r = 0; r < 4; ++r) {
            const int t = wv * 16 + lq * 4 + r;
            const int s = js * 16 + l15;
            const float cp = (t > 0) ? cums[t - 1] : 0.f;
            Ef[t * ESTR + s] = (s < t) ? __expf(cp - cums[s]) * accK[js][r] : 0.f;
            const float gv = (s <= t) ? __expf(cums[t] - cums[s]) * accQ4[js][r] : 0.f;
            Gc[t * 64 + s] = f2bf(gv);
        }
    }
    __syncthreads();

    // M-solve: lane s owns column s (self-contained, wave-lockstep)
    if (tid < 64) {
        const int s = tid;
        for (int r = 0; r < 64; ++r) Mf[r * ESTR + s] = 0.f;
        Mf[s * ESTR + s] = bv[s];
        for (int t = 1; t < 64; ++t) {
            float s0 = 0.f, s1 = 0.f;
            int r = 0;
            for (; r + 1 < t; r += 2) {
                s0 = fmaf(Ef[t * ESTR + r],     Mf[r * ESTR + s],       s0);
                s1 = fmaf(Ef[t * ESTR + r + 1], Mf[(r + 1) * ESTR + s], s1);
            }
            if (r < t) s0 = fmaf(Ef[t * ESTR + r], Mf[r * ESTR + s], s0);
            if (s < t) Mf[t * ESTR + s] = -bv[t] * (s0 + s1);
        }
    }
    __syncthreads();
    ushort* Mc = Mg + (size_t)cid * 4096;
#pragma unroll
    for (int j = 0; j < 16; ++j) {
        const int e = tid + j * 256;
        Mc[e] = f2bf(Mf[(e >> 6) * ESTR + (e & 63)]);
    }
    if (tid < 64) {
        const float cp = (tid > 0) ? cums[tid - 1] : 0.f;
        pug[cid * 64 + tid] = __expf(cp);
        pog[cid * 64 + tid] = __expf(cums[tid]);
        cg [cid * 64 + tid] = __expf(cums[63] - cums[tid]);
        if (tid == 0) dtotg[cid] = __expf(cums[63]);
    }
}

// ============ kernel S: 16 sequential chunks per (bh, dv-slice), all MFMA ====
// 64 blocks = 16 bh x 4 dv-slices of 32; 4 waves. State S[32][128] in f32 acc
// regs, fed to MFMA as hi/lo bf16 split (compensated).
__global__ __launch_bounds__(256)
void k_scan2(const float* __restrict__ klin, const float* __restrict__ qlin,
             const float* __restrict__ vlin,
             const ushort* __restrict__ Mg, const ushort* __restrict__ Gg,
             const float* __restrict__ pug, const float* __restrict__ pog,
             const float* __restrict__ cg, const float* __restrict__ dtotg,
             float* __restrict__ o)
{
    const int blk = blockIdx.x;          // bh*4 + rb
    const int bh = blk >> 2, rb = blk & 3;
    const int b = bh >> 3, h = bh & 7;
    const int tid = threadIdx.x;
    const int wv = tid >> 6, l = tid & 63, l15 = l & 15, lq = l >> 4;
    const int k8o = lq * 8;

    __shared__ ushort Kb[64 * KSTR], Qb[64 * KSTR];
    __shared__ ushort KTb[128 * 72];
    __shared__ float  Vtf[32 * 72];
    __shared__ ushort Mb[64 * 72], Gb[64 * 72];
    __shared__ ushort Shb[32 * KSTR], Slb[32 * KSTR];
    __shared__ ushort Yb[32 * 72], Wb[32 * 72], Wcb[32 * 72];
    __shared__ float  Otf[64 * 36];
    __shared__ float  puv[64], pov[64], cv2[64], dts[1];

    const int trow  = wv >> 1;           // dv tile row (0/1)
    const int tcol0 = (wv & 1) * 2;      // t tile cols {tcol0, tcol0+1}
    const int scol0 = (wv & 1) * 4;      // dk tile cols {scol0..scol0+3}

    f32x4 accS[4];
#pragma unroll
    for (int m = 0; m < 4; ++m) accS[m] = f32x4{0.f, 0.f, 0.f, 0.f};

    const float* kbase = klin + (size_t)b * TSEQ * HID_ + h * DK;
    const float* qbase = qlin + (size_t)b * TSEQ * HID_ + h * DK;
    const float* vbase = vlin + (size_t)b * TSEQ * HID_ + h * DV + rb * 32;
    float* obase = o + (size_t)bh * TSEQ * DV + rb * 32;

    for (int c = 0; c < NCK; ++c) {
        const int cid = bh * 16 + c;
        const int t0 = c * LCH;
        // ---- A: stage K,Q (+KT), V^T (f32), M, G, decays
#pragma unroll
        for (int j = 0; j < 8; ++j) {
            const int i4 = tid + j * 256;
            const int row = i4 >> 5, c4 = i4 & 31;
            float4 kv = *(const float4*)(kbase + (size_t)(t0 + row) * HID_ + c4 * 4);
            float4 qv = *(const float4*)(qbase + (size_t)(t0 + row) * HID_ + c4 * 4);
            uint2 kp; kp.x = pk2(kv.x, kv.y); kp.y = pk2(kv.z, kv.w);
            uint2 qp; qp.x = pk2(qv.x, qv.y); qp.y = pk2(qv.z, qv.w);
            *(uint2*)(Kb + row * KSTR + c4 * 4) = kp;
            *(uint2*)(Qb + row * KSTR + c4 * 4) = qp;
            KTb[(c4 * 4 + 0) * 72 + row] = (ushort)(kp.x & 0xffffu);
            KTb[(c4 * 4 + 1) * 72 + row] = (ushort)(kp.x >> 16);
            KTb[(c4 * 4 + 2) * 72 + row] = (ushort)(kp.y & 0xffffu);
            KTb[(c4 * 4 + 3) * 72 + row] = (ushort)(kp.y >> 16);
        }
#pragma unroll
        for (int j = 0; j < 2; ++j) {
            const int i4 = tid + j * 256;            // 0..511
            const int row = i4 >> 3, c4 = i4 & 7;
            float4 vv = *(const float4*)(vbase + (size_t)(t0 + row) * HID_ + c4 * 4);
            Vtf[(c4 * 4 + 0) * 72 + row] = vv.x;
            Vtf[(c4 * 4 + 1) * 72 + row] = vv.y;
            Vtf[(c4 * 4 + 2) * 72 + row] = vv.z;
            Vtf[(c4 * 4 + 3) * 72 + row] = vv.w;
        }
        const ushort* Mc = Mg + (size_t)cid * 4096;
        const ushort* Gc = Gg + (size_t)cid * 4096;
#pragma unroll
        for (int j = 0; j < 2; ++j) {
            const int i8 = tid + j * 256;            // 0..511 uint4s
            const int row = i8 >> 3, c8 = i8 & 7;
            *(uint4*)(Mb + row * 72 + c8 * 8) = *(const uint4*)(Mc + row * 64 + c8 * 8);
            *(uint4*)(Gb + row * 72 + c8 * 8) = *(const uint4*)(Gc + row * 64 + c8 * 8);
        }
        if (tid < 64) {
            puv[tid] = pug[cid * 64 + tid];
            pov[tid] = pog[cid * 64 + tid];
            cv2[tid] = cg[cid * 64 + tid];
            if (tid == 0) dts[0] = dtotg[cid];
        }
        __syncthreads();

        // ---- B: state -> LDS as hi/lo bf16
#pragma unroll
        for (int m = 0; m < 4; ++m) {
#pragma unroll
            for (int r = 0; r < 4; ++r) {
                const int dv = trow * 16 + lq * 4 + r;
                const int dk = (scol0 + m) * 16 + l15;
                const float sv = accS[m][r];
                const ushort hi = f2bf(sv);
                const float hf = __builtin_bit_cast(float, ((unsigned)hi) << 16);
                Shb[dv * KSTR + dk] = hi;
                Slb[dv * KSTR + dk] = f2bf(sv - hf);
            }
        }
        __syncthreads();

        // ---- C: U = S.K^T, UQ = S.Q^T  (compensated)
        f32x4 accU[2], accQ[2];
#pragma unroll
        for (int jj = 0; jj < 2; ++jj) {
            accU[jj] = f32x4{0.f, 0.f, 0.f, 0.f};
            accQ[jj] = f32x4{0.f, 0.f, 0.f, 0.f};
        }
#pragma unroll
        for (int kk = 0; kk < 4; ++kk) {
            short8 ah = *(const short8*)(Shb + (trow * 16 + l15) * KSTR + kk * 32 + k8o);
            short8 al = *(const short8*)(Slb + (trow * 16 + l15) * KSTR + kk * 32 + k8o);
#pragma unroll
            for (int jj = 0; jj < 2; ++jj) {
                short8 bk = *(const short8*)(Kb + ((tcol0 + jj) * 16 + l15) * KSTR + kk * 32 + k8o);
                short8 bq = *(const short8*)(Qb + ((tcol0 + jj) * 16 + l15) * KSTR + kk * 32 + k8o);
                accU[jj] = MFMA(ah, bk, accU[jj], 0, 0, 0);
                accU[jj] = MFMA(al, bk, accU[jj], 0, 0, 0);
                accQ[jj] = MFMA(ah, bq, accQ[jj], 0, 0, 0);
                accQ[jj] = MFMA(al, bq, accQ[jj], 0, 0, 0);
            }
        }
        // ---- D: Y = V^T - pu (.) U   (f32, then bf16)
#pragma unroll
        for (int jj = 0; jj < 2; ++jj) {
#pragma unroll
            for (int r = 0; r < 4; ++r) {
                const int t = (tcol0 + jj) * 16 + l15;
                const int dv = trow * 16 + lq * 4 + r;
                const float y = Vtf[dv * 72 + t] - puv[t] * accU[jj][r];
                Yb[dv * 72 + t] = f2bf(y);
            }
        }
        __syncthreads();

        // ---- E: W = Y M^T-form (mfma over s)
        f32x4 accW[2];
#pragma unroll
        for (int jj = 0; jj < 2; ++jj) accW[jj] = f32x4{0.f, 0.f, 0.f, 0.f};
#pragma unroll
        for (int kk = 0; kk < 2; ++kk) {
            short8 ay = *(const short8*)(Yb + (trow * 16 + l15) * 72 + kk * 32 + k8o);
#pragma unroll
            for (int jj = 0; jj < 2; ++jj) {
                short8 bm = *(const short8*)(Mb + ((tcol0 + jj) * 16 + l15) * 72 + kk * 32 + k8o);
                accW[jj] = MFMA(ay, bm, accW[jj], 0, 0, 0);
            }
        }
#pragma unroll
        for (int jj = 0; jj < 2; ++jj) {
#pragma unroll
            for (int r = 0; r < 4; ++r) {
                const int t = (tcol0 + jj) * 16 + l15;
                const int dv = trow * 16 + lq * 4 + r;
                const float wvl = accW[jj][r];
                Wb[dv * 72 + t]  = f2bf(wvl);
                Wcb[dv * 72 + t] = f2bf(wvl * cv2[t]);
            }
        }
        __syncthreads();

        // ---- F: O = po (.) UQ + G W ; ---- G: S = dtot*S + Wc K
        f32x4 accO[2];
#pragma unroll
        for (int jj = 0; jj < 2; ++jj) accO[jj] = f32x4{0.f, 0.f, 0.f, 0.f};
#pragma unroll
        for (int kk = 0; kk < 2; ++kk) {
            short8 aw = *(const short8*)(Wb + (trow * 16 + l15) * 72 + kk * 32 + k8o);
#pragma unroll
            for (int jj = 0; jj < 2; ++jj) {
                short8 bg = *(const short8*)(Gb + ((tcol0 + jj) * 16 + l15) * 72 + kk * 32 + k8o);
                accO[jj] = MFMA(aw, bg, accO[jj], 0, 0, 0);
            }
        }
#pragma unroll
        for (int jj = 0; jj < 2; ++jj) {
#pragma unroll
            for (int r = 0; r < 4; ++r) {
                const int t = (tcol0 + jj) * 16 + l15;
                const int dv = trow * 16 + lq * 4 + r;
                Otf[t * 36 + dv] = pov[t] * accQ[jj][r] + accO[jj][r];
            }
        }
        const float dt = dts[0];
#pragma unroll
        for (int m = 0; m < 4; ++m)
#pragma unroll
            for (int r = 0; r < 4; ++r) accS[m][r] *= dt;
#pragma unroll
        for (int kk = 0; kk < 2; ++kk) {
            short8 aw = *(const short8*)(Wcb + (trow * 16 + l15) * 72 + kk * 32 + k8o);
#pragma unroll
            for (int m = 0; m < 4; ++m) {
                short8 bk = *(const short8*)(KTb + ((scol0 + m) * 16 + l15) * 72 + kk * 32 + k8o);
                accS[m] = MFMA(aw, bk, accS[m], 0, 0, 0);
            }
        }
        __syncthreads();

        // ---- H: coalesced O store
#pragma unroll
        for (int j = 0; j < 2; ++j) {
            const int i4 = tid + j * 256;            // 0..511
            const int row = i4 >> 3, c4 = i4 & 7;
            float4 ov = *(const float4*)(Otf + row * 36 + c4 * 4);
            *(float4*)(obase + (size_t)(t0 + row) * DV + c4 * 4) = ov;
        }
        __syncthreads();
    }
}

// ---------------- LayerNorm(Dv) + sigmoid gate ----------------
__global__ __launch_bounds__(256)
void k_ln_gate(const float* __restrict__ o, const float* __restrict__ g_lin,
               const float* __restrict__ ln_g, const float* __restrict__ ln_b,
               float* __restrict__ og)
{
    const int idx  = blockIdx.x * 4 + (threadIdx.x >> 6);
    const int lane = threadIdx.x & 63;
    const int h  = idx & 7;
    const int bt = idx >> 3;
    const int b  = bt >> 10;
    const int t  = bt & 1023;
    const float* op = o + ((size_t)(b * NH + h) * TSEQ + t) * DV;
    float2 xv = ((const float2*)op)[lane];
    float s = xv.x + xv.y;
#pragma unroll
    for (int m = 32; m; m >>= 1) s += __shfl_xor(s, m);
    const float mu = s * (1.f / 128.f);
    const float d0 = xv.x - mu, d1 = xv.y - mu;
    float v = d0 * d0 + d1 * d1;
#pragma unroll
    for (int m = 32; m; m >>= 1) v += __shfl_xor(v, m);
    const float inv = rsqrtf(v * (1.f / 128.f) + 1e-5f);
    const int d = lane * 2;
    const float* gp = g_lin + (size_t)bt * HID_ + h * DV;
    const float g0 = sig_(gp[d]), g1 = sig_(gp[d + 1]);
    const float y0 = (d0 * inv * ln_g[d]     + ln_b[d])     * g0;
    const float y1 = (d1 * inv * ln_g[d + 1] + ln_b[d + 1]) * g1;
    ((float2*)(og + (size_t)bt * HID_ + h * DV))[lane] = make_float2(y0, y1);
}

extern "C" void kernel_launch(void* const* d_in, const int* in_sizes, int n_in,
                              void* d_out, int out_size, void* d_ws, size_t ws_size,
                              hipStream_t stream)
{
    const float* x   = (const float*)d_in[0];
    const float* Wq  = (const float*)d_in[1];
    const float* Wk  = (const float*)d_in[2];
    const float* Wv  = (const float*)d_in[3];
    const float* cqw = (const float*)d_in[4];
    const float* cqb = (const float*)d_in[5];
    const float* ckw = (const float*)d_in[6];
    const float* ckb = (const float*)d_in[7];
    const float* cvw = (const float*)d_in[8];
    const float* cvb = (const float*)d_in[9];
    const float* Wa  = (const float*)d_in[10];
    const float* ba  = (const float*)d_in[11];
    const float* Wb  = (const float*)d_in[12];
    const float* bb  = (const float*)d_in[13];
    const float* Wg  = (const float*)d_in[14];
    const float* Wo  = (const float*)d_in[15];
    const float* lng = (const float*)d_in[16];
    const float* lnb = (const float*)d_in[17];
    float* out = (float*)d_out;
    float* ws  = (float*)d_ws;

    float* q_lin = ws;
    float* k_lin = ws + 1 * (size_t)SZf;
    float* v_lin = ws + 2 * (size_t)SZf;
    float* g_lin = ws + 3 * (size_t)SZf;
    float* o_buf = ws + 4 * (size_t)SZf;     // WT4 -> conv scratch -> scan out
    float* aT    = ws + 5 * (size_t)SZf;
    float* bT    = aT + 16 * TSEQ;
    float* pug   = bT + 16 * TSEQ;
    float* pog   = pug + 256 * 64;
    float* cgd   = pog + 256 * 64;
    float* dtg   = cgd + 256 * 64;           // 256 floats
    float* og    = ws;                        // reuse q_lin after scan

    ushort* WT4 = (ushort*)o_buf;            // dead after gemm4
    ushort* WoT = (ushort*)k_lin;            // written after scan
    ushort* Mg  = (ushort*)out;              // 2MB, dead before final gemm writes out
    ushort* Gg  = Mg + 256 * 4096;           // 2MB

    k_wT<<<dim3(16, 16, 4), 256, 0, stream>>>(Wq, Wk, Wv, Wg, WT4);
    k_gemm4<<<dim3(8, 16, 4), 256, 0, stream>>>(x, WT4, ws);
    k_ab<<<ROWS, 64, 0, stream>>>(x, Wa, ba, Wb, bb, aT, bT);
    k_conv_save<<<dim3(15, 2, 3), 256, 0, stream>>>(q_lin, k_lin, v_lin, o_buf);
    k_conv_apply<<<dim3(64, 2, 3), 256, 0, stream>>>(q_lin, k_lin, v_lin, o_buf,
                                                     cqw, cqb, ckw, ckb, cvw, cvb);
    k_prep<<<256, 256, 0, stream>>>(k_lin, q_lin, aT, bT, Mg, Gg, pug, pog, cgd, dtg);
    k_scan2<<<64, 256, 0, stream>>>(k_lin, q_lin, v_lin, Mg, Gg, pug, pog, cgd, dtg, o_buf);
    k_wT<<<dim3(16, 16, 1), 256, 0, stream>>>(Wo, Wo, Wo, Wo, WoT);
    k_ln_gate<<<4096, 256, 0, stream>>>(o_buf, g_lin, lng, lnb, og);
    k_gemm1<<<dim3(8, 16), 256, 0, stream>>>(og, WoT, out);
}

// Round 8
// 230.412 us; speedup vs baseline: 3.1738x; 1.0819x over previous
//
#include <hip/hip_runtime.h>

#define TSEQ 1024
#define HID_ 1024
#define NH 8
#define DK 128
#define DV 128
#define ROWS 2048               // B*T
#define SZf (ROWS * HID_)       // floats per [2048,1024] matrix
#define LCH 64                  // scan chunk length
#define NCK 16                  // chunks per (b,h)
#define KSTR 136                // bf16 LDS stride for [64][128] tiles
#define ESTR 65

typedef __attribute__((ext_vector_type(8))) short short8;
typedef __attribute__((ext_vector_type(4))) float f32x4;
#define MFMA __builtin_amdgcn_mfma_f32_16x16x32_bf16

__device__ __forceinline__ float sig_(float x) { return 1.f / (1.f + __expf(-x)); }

__device__ __forceinline__ ushort f2bf(float f) {   // RNE f32->bf16
    unsigned int u = __builtin_bit_cast(unsigned int, f);
    u += 0x7FFF + ((u >> 16) & 1);
    return (ushort)(u >> 16);
}
__device__ __forceinline__ unsigned int pk2(float lo, float hi) {
    return (unsigned int)f2bf(lo) | ((unsigned int)f2bf(hi) << 16);
}

// ---------------- x -> bf16 ----------------
__global__ __launch_bounds__(256)
void k_x2bf(const float* __restrict__ x, ushort* __restrict__ xb)
{
    const size_t i8 = (size_t)blockIdx.x * 256 + threadIdx.x;   // grid 1024
    float4 v0 = *(const float4*)(x + i8 * 8);
    float4 v1 = *(const float4*)(x + i8 * 8 + 4);
    uint4 o;
    o.x = pk2(v0.x, v0.y); o.y = pk2(v0.z, v0.w);
    o.z = pk2(v1.x, v1.y); o.w = pk2(v1.z, v1.w);
    *(uint4*)(xb + i8 * 8) = o;
}

// ---------------- weight transpose+convert: W f32 [K][N] -> WT bf16 [N][K] ----
__global__ __launch_bounds__(256)
void k_wT(const float* __restrict__ s0, const float* __restrict__ s1,
          const float* __restrict__ s2, const float* __restrict__ s3,
          ushort* __restrict__ dst)
{
    const int z = blockIdx.z;
    const float* W = (z == 0) ? s0 : (z == 1) ? s1 : (z == 2) ? s2 : s3;
    ushort* WT = dst + (size_t)z * (1024 * 1024);
    __shared__ float t[64][65];
    const int n0 = blockIdx.x * 64, k0 = blockIdx.y * 64;
    const int rr = threadIdx.x >> 4, cc = threadIdx.x & 15;
#pragma unroll
    for (int i = 0; i < 4; ++i) {
        const int row = i * 16 + rr;
        float4 v = *(const float4*)(W + (size_t)(k0 + row) * 1024 + n0 + cc * 4);
        t[row][cc * 4 + 0] = v.x; t[row][cc * 4 + 1] = v.y;
        t[row][cc * 4 + 2] = v.z; t[row][cc * 4 + 3] = v.w;
    }
    __syncthreads();
#pragma unroll
    for (int i = 0; i < 4; ++i) {
        const int n = i * 16 + rr;
        const int kc = cc * 4;
        ushort4 o;
        o.x = f2bf(t[kc + 0][n]); o.y = f2bf(t[kc + 1][n]);
        o.z = f2bf(t[kc + 2][n]); o.w = f2bf(t[kc + 3][n]);
        *(ushort4*)(WT + (size_t)(n0 + n) * 1024 + k0 + kc) = o;
    }
}

// ------------- bf16 MFMA GEMM: C = A(bf16 [M][K]) x BT(bf16 [N][K]) -------------
#define LDSB 40
__device__ __forceinline__ void gemm_tile_mfma(const ushort* __restrict__ A,
                                               const ushort* __restrict__ BT,
                                               float* __restrict__ C,
                                               int brow, int bcol)
{
    __shared__ ushort As[128 * LDSB];
    __shared__ ushort Bs[128 * LDSB];
    const int tid  = threadIdx.x;
    const int lane = tid & 63;
    const int wv   = tid >> 6;
    const int wm   = (wv >> 1) * 64;
    const int wn   = (wv & 1) * 64;
    const int l15  = lane & 15;
    const int k8   = (lane >> 4) * 8;
    const int srow = tid >> 1;
    const int skh  = (tid & 1) * 16;

    f32x4 acc[4][4];
#pragma unroll
    for (int i = 0; i < 4; ++i)
#pragma unroll
        for (int j = 0; j < 4; ++j)
#pragma unroll
            for (int e = 0; e < 4; ++e) acc[i][j][e] = 0.f;

    const ushort* arow = A  + (size_t)(brow + srow) * 1024 + skh;
    const ushort* brp  = BT + (size_t)(bcol + srow) * 1024 + skh;
    ushort* asw = As + srow * LDSB + skh;
    ushort* bsw = Bs + srow * LDSB + skh;

    for (int k0 = 0; k0 < 1024; k0 += 32) {
        uint4 a0 = *(const uint4*)(arow + k0);
        uint4 a1 = *(const uint4*)(arow + k0 + 8);
        uint4 b0 = *(const uint4*)(brp + k0);
        uint4 b1 = *(const uint4*)(brp + k0 + 8);
        __syncthreads();
        *(uint4*)(asw)     = a0;
        *(uint4*)(asw + 8) = a1;
        *(uint4*)(bsw)     = b0;
        *(uint4*)(bsw + 8) = b1;
        __syncthreads();
        short8 af[4], bf[4];
#pragma unroll
        for (int i = 0; i < 4; ++i)
            af[i] = *(const short8*)(As + (wm + i * 16 + l15) * LDSB + k8);
#pragma unroll
        for (int j = 0; j < 4; ++j)
            bf[j] = *(const short8*)(Bs + (wn + j * 16 + l15) * LDSB + k8);
#pragma unroll
        for (int i = 0; i < 4; ++i)
#pragma unroll
            for (int j = 0; j < 4; ++j)
                acc[i][j] = MFMA(af[i], bf[j], acc[i][j], 0, 0, 0);
    }
    const int l4 = lane >> 4;
#pragma unroll
    for (int i = 0; i < 4; ++i)
#pragma unroll
        for (int j = 0; j < 4; ++j)
#pragma unroll
            for (int r = 0; r < 4; ++r)
                C[(size_t)(brow + wm + i * 16 + l4 * 4 + r) * 1024 +
                  bcol + wn + j * 16 + l15] = acc[i][j][r];
}

__global__ __launch_bounds__(256)
void k_gemm4(const ushort* __restrict__ A, const ushort* __restrict__ WT,
             float* __restrict__ Cbase)
{
    const ushort* BT = WT + (size_t)blockIdx.z * (1024 * 1024);
    float* C = Cbase + (size_t)blockIdx.z * SZf;
    gemm_tile_mfma(A, BT, C, blockIdx.y * 128, blockIdx.x * 128);
}

__global__ __launch_bounds__(256)
void k_gemm1(const ushort* __restrict__ A, const ushort* __restrict__ BT,
             float* __restrict__ C)
{
    gemm_tile_mfma(A, BT, C, blockIdx.y * 128, blockIdx.x * 128);
}

// -------- alpha/beta small GEMM + sigmoid; writes TRANSPOSED [bh][t] --------
__global__ __launch_bounds__(64)
void k_ab(const float* __restrict__ x, const float* __restrict__ Wa,
          const float* __restrict__ ba, const float* __restrict__ Wb,
          const float* __restrict__ bb, float* __restrict__ aT,
          float* __restrict__ bT)
{
    const int r = blockIdx.x;
    const int lane = threadIdx.x;
    const int b = r >> 10, t = r & 1023;
    const float* xr = x + (size_t)r * HID_;
    float acc[16];
#pragma unroll
    for (int n = 0; n < 16; ++n) acc[n] = 0.f;
    for (int c = lane; c < HID_; c += 64) {
        const float xv = xr[c];
        const float* wa = Wa + c * 8;
        const float* wb = Wb + c * 8;
#pragma unroll
        for (int n = 0; n < 8; ++n) {
            acc[n]     = fmaf(xv, wa[n], acc[n]);
            acc[8 + n] = fmaf(xv, wb[n], acc[8 + n]);
        }
    }
#pragma unroll
    for (int n = 0; n < 16; ++n) {
#pragma unroll
        for (int m = 32; m; m >>= 1) acc[n] += __shfl_xor(acc[n], m);
    }
    if (lane < 8) {
        aT[(size_t)(b * 8 + lane) * TSEQ + t] = sig_(acc[lane] + ba[lane]);
        bT[(size_t)(b * 8 + lane) * TSEQ + t] = sig_(acc[8 + lane] + bb[lane]);
    }
}

// -------- causal depthwise conv K=4 + SiLU (+scale), in-place, T-parallel ----
__global__ __launch_bounds__(256)
void k_conv_save(const float* __restrict__ q, const float* __restrict__ k,
                 const float* __restrict__ v, float* __restrict__ scr)
{
    const int z = blockIdx.z, b = blockIdx.y, j = blockIdx.x + 1;
    const float* y = (z == 0) ? q : (z == 1) ? k : v;
    float* d = scr + ((size_t)(z * 2 + b) * 15 + (j - 1)) * 3 * 1024;
    const float* s = y + ((size_t)b * TSEQ + j * 64 - 3) * HID_;
    for (int i = threadIdx.x; i < 3 * 1024; i += 256)
        d[i] = s[i];
}

__global__ __launch_bounds__(256)
void k_conv_apply(float* __restrict__ q, float* __restrict__ k, float* __restrict__ v,
                  const float* __restrict__ scr,
                  const float* __restrict__ wq, const float* __restrict__ bq,
                  const float* __restrict__ wk, const float* __restrict__ bk,
                  const float* __restrict__ wv, const float* __restrict__ bv)
{
    const int z = blockIdx.z, b = blockIdx.y;
    const int j = blockIdx.x >> 2, cg = blockIdx.x & 3;
    float* y          = (z == 0) ? q  : (z == 1) ? k  : v;
    const float* w    = (z == 0) ? wq : (z == 1) ? wk : wv;
    const float* bias = (z == 0) ? bq : (z == 1) ? bk : bv;
    const float scale = (z == 1) ? 0.08838834764831845f : 1.f;
    const int c = cg * 256 + threadIdx.x;
    const float w0 = w[c * 4], w1 = w[c * 4 + 1], w2 = w[c * 4 + 2], w3 = w[c * 4 + 3];
    const float bs = bias[c];
    float y0 = 0.f, y1 = 0.f, y2 = 0.f;
    if (j > 0) {
        const float* s = scr + ((size_t)(z * 2 + b) * 15 + (j - 1)) * 3 * 1024 + c;
        y0 = s[0]; y1 = s[1024]; y2 = s[2048];
    }
    float* yp = y + ((size_t)b * TSEQ + j * 64) * HID_ + c;
#pragma unroll 4
    for (int t = 0; t < 64; ++t) {
        float y3  = yp[(size_t)t * HID_];
        float acc = fmaf(w0, y0, fmaf(w1, y1, fmaf(w2, y2, fmaf(w3, y3, bs))));
        float sv  = acc * sig_(acc) * scale;
        yp[(size_t)t * HID_] = sv;
        y0 = y1; y1 = y2; y2 = y3;
    }
}

// ---------- k_stage: pre-format K,Q (bf16, chunk layout) + KT per chunk ------
__global__ __launch_bounds__(256)
void k_stage(const float* __restrict__ klin, const float* __restrict__ qlin,
             ushort* __restrict__ Kst, ushort* __restrict__ Qst,
             ushort* __restrict__ KTst)
{
    const int cid = blockIdx.x;          // bh*16 + c
    const int bh = cid >> 4, c = cid & 15;
    const int b = bh >> 3, h = bh & 7;
    const int tid = threadIdx.x;
    const int t0 = c * LCH;
    __shared__ ushort Kl[64 * KSTR];
    const float* kb = klin + ((size_t)b * TSEQ + t0) * HID_ + h * DK;
    const float* qb = qlin + ((size_t)b * TSEQ + t0) * HID_ + h * DK;
    const size_t go = (size_t)cid * 8192;
#pragma unroll
    for (int j = 0; j < 8; ++j) {
        const int i4 = tid + j * 256;
        const int row = i4 >> 5, c4 = i4 & 31;
        float4 kv = *(const float4*)(kb + (size_t)row * HID_ + c4 * 4);
        float4 qv = *(const float4*)(qb + (size_t)row * HID_ + c4 * 4);
        uint2 kp; kp.x = pk2(kv.x, kv.y); kp.y = pk2(kv.z, kv.w);
        uint2 qp; qp.x = pk2(qv.x, qv.y); qp.y = pk2(qv.z, qv.w);
        *(uint2*)(Kst + go + row * 128 + c4 * 4) = kp;
        *(uint2*)(Qst + go + row * 128 + c4 * 4) = qp;
        *(uint2*)(Kl + row * KSTR + c4 * 4) = kp;
    }
    __syncthreads();
#pragma unroll
    for (int j = 0; j < 4; ++j) {                 // KT [dk][t]
        const int o8 = tid + j * 256;
        const int dk = o8 >> 3, tt = (o8 & 7) * 8;
        ushort tmp[8];
#pragma unroll
        for (int e = 0; e < 8; ++e) tmp[e] = Kl[(tt + e) * KSTR + dk];
        *(uint4*)(KTst + go + dk * 64 + tt) = *(uint4*)tmp;
    }
}

// ============ kernel P: per-chunk parallel precompute (M, G, decays) =========
__global__ __launch_bounds__(256)
void k_prep(const ushort* __restrict__ Kst, const ushort* __restrict__ Qst,
            const float* __restrict__ aT, const float* __restrict__ bT,
            ushort* __restrict__ Mg, ushort* __restrict__ Gg,
            float* __restrict__ pug, float* __restrict__ pog,
            float* __restrict__ cg, float* __restrict__ dtotg)
{
    const int cid = blockIdx.x;
    const int bh = cid >> 4, c = cid & 15;
    const int tid = threadIdx.x;
    const int t0 = c * LCH;

    __shared__ ushort Kb[64 * KSTR], Qb[64 * KSTR];
    __shared__ float Ef[64 * ESTR];
    __shared__ float Mf[64 * ESTR];
    __shared__ float cums[64], bv[64];

    if (tid < 64) {
        const float a = aT[(size_t)bh * TSEQ + t0 + tid];
        bv[tid] = bT[(size_t)bh * TSEQ + t0 + tid];
        float cs = __logf(a);
#pragma unroll
        for (int d = 1; d < 64; d <<= 1) {
            float pv = __shfl_up(cs, d);
            if (tid >= d) cs += pv;
        }
        cums[tid] = cs;
    }
    const size_t go = (size_t)cid * 8192;
#pragma unroll
    for (int j = 0; j < 4; ++j) {
        const int i16 = tid + j * 256;
        const int row = i16 >> 4, col = (i16 & 15) * 8;
        *(uint4*)(Kb + row * KSTR + col) = *(const uint4*)(Kst + go + i16 * 8);
        *(uint4*)(Qb + row * KSTR + col) = *(const uint4*)(Qst + go + i16 * 8);
    }
    __syncthreads();

    const int wv = tid >> 6, l = tid & 63, l15 = l & 15, lq = l >> 4;
    const int k8o = lq * 8;
    f32x4 accK[4], accQ4[4];
#pragma unroll
    for (int j = 0; j < 4; ++j) {
        accK[j] = f32x4{0.f, 0.f, 0.f, 0.f};
        accQ4[j] = f32x4{0.f, 0.f, 0.f, 0.f};
    }
#pragma unroll
    for (int kk = 0; kk < 4; ++kk) {
        short8 aK = *(const short8*)(Kb + (wv * 16 + l15) * KSTR + kk * 32 + k8o);
        short8 aQ = *(const short8*)(Qb + (wv * 16 + l15) * KSTR + kk * 32 + k8o);
#pragma unroll
        for (int js = 0; js < 4; ++js) {
            short8 bK = *(const short8*)(Kb + (js * 16 + l15) * KSTR + kk * 32 + k8o);
            accK[js]  = MFMA(aK, bK, accK[js], 0, 0, 0);
            accQ4[js] = MFMA(aQ, bK, accQ4[js], 0, 0, 0);
        }
    }
    ushort* Gc = Gg + (size_t)cid * 4096;
#pragma unroll
    for (int js = 0; js < 4; ++js) {
#pragma unroll
        for (int r = 0; r < 4; ++r) {
            const int t = wv * 16 + lq * 4 + r;
            const int s = js * 16 + l15;
            const float cp = (t > 0) ? cums[t - 1] : 0.f;
            Ef[t * ESTR + s] = (s < t) ? __expf(cp - cums[s]) * accK[js][r] : 0.f;
            const float gv = (s <= t) ? __expf(cums[t] - cums[s]) * accQ4[js][r] : 0.f;
            Gc[t * 64 + s] = f2bf(gv);
        }
    }
    __syncthreads();

    if (tid < 64) {                     // M-solve: lane s owns column s
        const int s = tid;
        for (int r = 0; r < 64; ++r) Mf[r * ESTR + s] = 0.f;
        Mf[s * ESTR + s] = bv[s];
        for (int t = 1; t < 64; ++t) {
            float s0 = 0.f, s1 = 0.f;
            int r = 0;
            for (; r + 1 < t; r += 2) {
                s0 = fmaf(Ef[t * ESTR + r],     Mf[r * ESTR + s],       s0);
                s1 = fmaf(Ef[t * ESTR + r + 1], Mf[(r + 1) * ESTR + s], s1);
            }
            if (r < t) s0 = fmaf(Ef[t * ESTR + r], Mf[r * ESTR + s], s0);
            if (s < t) Mf[t * ESTR + s] = -bv[t] * (s0 + s1);
        }
    }
    __syncthreads();
    ushort* Mc = Mg + (size_t)cid * 4096;
#pragma unroll
    for (int j = 0; j < 16; ++j) {
        const int e = tid + j * 256;
        Mc[e] = f2bf(Mf[(e >> 6) * ESTR + (e & 63)]);
    }
    if (tid < 64) {
        const float cp = (tid > 0) ? cums[tid - 1] : 0.f;
        pug[cid * 64 + tid] = __expf(cp);
        pog[cid * 64 + tid] = __expf(cums[tid]);
        cg [cid * 64 + tid] = __expf(cums[63] - cums[tid]);
        if (tid == 0) dtotg[cid] = __expf(cums[63]);
    }
}

// ============ kernel S: 16 sequential chunks, staged bf16 + reg prefetch =====
__global__ __launch_bounds__(256)
void k_scan2(const ushort* __restrict__ Kst, const ushort* __restrict__ Qst,
             const ushort* __restrict__ KTst, const float* __restrict__ vlin,
             const ushort* __restrict__ Mg, const ushort* __restrict__ Gg,
             const float* __restrict__ pug, const float* __restrict__ pog,
             const float* __restrict__ cg, const float* __restrict__ dtotg,
             float* __restrict__ o)
{
    const int blk = blockIdx.x;          // bh*4 + rb
    const int bh = blk >> 2, rb = blk & 3;
    const int b = bh >> 3, h = bh & 7;
    const int tid = threadIdx.x;
    const int wv = tid >> 6, l = tid & 63, l15 = l & 15, lq = l >> 4;
    const int k8o = lq * 8;

    __shared__ ushort Kb[64 * KSTR], Qb[64 * KSTR];
    __shared__ ushort KTb[128 * 72];
    __shared__ float  Vtf[32 * 72];
    __shared__ ushort Mb[64 * 72], Gb[64 * 72];
    __shared__ ushort Shb[32 * KSTR], Slb[32 * KSTR];
    __shared__ ushort Yb[32 * 72], Wb[32 * 72], Wcb[32 * 72];
    __shared__ float  Otf[64 * 36];
    __shared__ float  puv[64], pov[64], cv2[64], dts[1];

    const int trow  = wv >> 1;
    const int tcol0 = (wv & 1) * 2;
    const int scol0 = (wv & 1) * 4;

    f32x4 accS[4];
#pragma unroll
    for (int m = 0; m < 4; ++m) accS[m] = f32x4{0.f, 0.f, 0.f, 0.f};

    const float* vbase = vlin + (size_t)b * TSEQ * HID_ + h * DV + rb * 32;
    float* obase = o + (size_t)bh * TSEQ * DV + rb * 32;

    // prefetch registers
    uint4 rk[4], rq[4], rkt[4], rm[2], rg[2];
    float4 rv[2];
    float rpu = 0.f, rpo = 0.f, rcv = 0.f, rdt = 0.f;

    auto LOADC = [&](int cc) {
        const int cid = bh * 16 + cc;
        const size_t go = (size_t)cid * 8192;
#pragma unroll
        for (int j = 0; j < 4; ++j) {
            rk[j]  = *(const uint4*)(Kst  + go + (tid + j * 256) * 8);
            rq[j]  = *(const uint4*)(Qst  + go + (tid + j * 256) * 8);
            rkt[j] = *(const uint4*)(KTst + go + (tid + j * 256) * 8);
        }
#pragma unroll
        for (int j = 0; j < 2; ++j) {
            rm[j] = *(const uint4*)(Mg + (size_t)cid * 4096 + (tid + j * 256) * 8);
            rg[j] = *(const uint4*)(Gg + (size_t)cid * 4096 + (tid + j * 256) * 8);
            const int i4 = tid + j * 256;
            rv[j] = *(const float4*)(vbase + (size_t)(cc * LCH + (i4 >> 3)) * HID_ + (i4 & 7) * 4);
        }
        if (tid < 64) {
            rpu = pug[cid * 64 + tid];
            rpo = pog[cid * 64 + tid];
            rcv = cg [cid * 64 + tid];
            if (tid == 0) rdt = dtotg[cid];
        }
    };
    auto WRITEC = [&]() {
#pragma unroll
        for (int j = 0; j < 4; ++j) {
            const int i16 = tid + j * 256;
            *(uint4*)(Kb  + (i16 >> 4) * KSTR + (i16 & 15) * 8) = rk[j];
            *(uint4*)(Qb  + (i16 >> 4) * KSTR + (i16 & 15) * 8) = rq[j];
            *(uint4*)(KTb + (i16 >> 3) * 72   + (i16 & 7) * 8)  = rkt[j];
        }
#pragma unroll
        for (int j = 0; j < 2; ++j) {
            const int i8 = tid + j * 256;
            *(uint4*)(Mb + (i8 >> 3) * 72 + (i8 & 7) * 8) = rm[j];
            *(uint4*)(Gb + (i8 >> 3) * 72 + (i8 & 7) * 8) = rg[j];
            const int i4 = tid + j * 256;
            const int row = i4 >> 3, c4 = i4 & 7;
            Vtf[(c4 * 4 + 0) * 72 + row] = rv[j].x;
            Vtf[(c4 * 4 + 1) * 72 + row] = rv[j].y;
            Vtf[(c4 * 4 + 2) * 72 + row] = rv[j].z;
            Vtf[(c4 * 4 + 3) * 72 + row] = rv[j].w;
        }
        if (tid < 64) {
            puv[tid] = rpu; pov[tid] = rpo; cv2[tid] = rcv;
            if (tid == 0) dts[0] = rdt;
        }
    };

    LOADC(0);
    WRITEC();
    __syncthreads();

    for (int c = 0; c < NCK; ++c) {
        const int t0 = c * LCH;
        if (c + 1 < NCK) LOADC(c + 1);          // in flight through compute

        // ---- B: state -> LDS as hi/lo bf16
#pragma unroll
        for (int m = 0; m < 4; ++m) {
#pragma unroll
            for (int r = 0; r < 4; ++r) {
                const int dv = trow * 16 + lq * 4 + r;
                const int dk = (scol0 + m) * 16 + l15;
                const float sv = accS[m][r];
                const ushort hi = f2bf(sv);
                const float hf = __builtin_bit_cast(float, ((unsigned)hi) << 16);
                Shb[dv * KSTR + dk] = hi;
                Slb[dv * KSTR + dk] = f2bf(sv - hf);
            }
        }
        __syncthreads();

        // ---- C: U = S.K^T, UQ = S.Q^T  (compensated)
        f32x4 accU[2], accQ[2];
#pragma unroll
        for (int jj = 0; jj < 2; ++jj) {
            accU[jj] = f32x4{0.f, 0.f, 0.f, 0.f};
            accQ[jj] = f32x4{0.f, 0.f, 0.f, 0.f};
        }
#pragma unroll
        for (int kk = 0; kk < 4; ++kk) {
            short8 ah = *(const short8*)(Shb + (trow * 16 + l15) * KSTR + kk * 32 + k8o);
            short8 al = *(const short8*)(Slb + (trow * 16 + l15) * KSTR + kk * 32 + k8o);
#pragma unroll
            for (int jj = 0; jj < 2; ++jj) {
                short8 bk = *(const short8*)(Kb + ((tcol0 + jj) * 16 + l15) * KSTR + kk * 32 + k8o);
                short8 bq = *(const short8*)(Qb + ((tcol0 + jj) * 16 + l15) * KSTR + kk * 32 + k8o);
                accU[jj] = MFMA(ah, bk, accU[jj], 0, 0, 0);
                accU[jj] = MFMA(al, bk, accU[jj], 0, 0, 0);
                accQ[jj] = MFMA(ah, bq, accQ[jj], 0, 0, 0);
                accQ[jj] = MFMA(al, bq, accQ[jj], 0, 0, 0);
            }
        }
        // ---- D: Y = V^T - pu (.) U
#pragma unroll
        for (int jj = 0; jj < 2; ++jj) {
#pragma unroll
            for (int r = 0; r < 4; ++r) {
                const int t = (tcol0 + jj) * 16 + l15;
                const int dv = trow * 16 + lq * 4 + r;
                const float y = Vtf[dv * 72 + t] - puv[t] * accU[jj][r];
                Yb[dv * 72 + t] = f2bf(y);
            }
        }
        __syncthreads();

        // ---- E: W = M-solve applied
        f32x4 accW[2];
#pragma unroll
        for (int jj = 0; jj < 2; ++jj) accW[jj] = f32x4{0.f, 0.f, 0.f, 0.f};
#pragma unroll
        for (int kk = 0; kk < 2; ++kk) {
            short8 ay = *(const short8*)(Yb + (trow * 16 + l15) * 72 + kk * 32 + k8o);
#pragma unroll
            for (int jj = 0; jj < 2; ++jj) {
                short8 bm = *(const short8*)(Mb + ((tcol0 + jj) * 16 + l15) * 72 + kk * 32 + k8o);
                accW[jj] = MFMA(ay, bm, accW[jj], 0, 0, 0);
            }
        }
#pragma unroll
        for (int jj = 0; jj < 2; ++jj) {
#pragma unroll
            for (int r = 0; r < 4; ++r) {
                const int t = (tcol0 + jj) * 16 + l15;
                const int dv = trow * 16 + lq * 4 + r;
                const float wvl = accW[jj][r];
                Wb[dv * 72 + t]  = f2bf(wvl);
                Wcb[dv * 72 + t] = f2bf(wvl * cv2[t]);
            }
        }
        __syncthreads();

        // ---- F: O = po (.) UQ + G W
        f32x4 accO[2];
#pragma unroll
        for (int jj = 0; jj < 2; ++jj) accO[jj] = f32x4{0.f, 0.f, 0.f, 0.f};
#pragma unroll
        for (int kk = 0; kk < 2; ++kk) {
            short8 aw = *(const short8*)(Wb + (trow * 16 + l15) * 72 + kk * 32 + k8o);
#pragma unroll
            for (int jj = 0; jj < 2; ++jj) {
                short8 bg = *(const short8*)(Gb + ((tcol0 + jj) * 16 + l15) * 72 + kk * 32 + k8o);
                accO[jj] = MFMA(aw, bg, accO[jj], 0, 0, 0);
            }
        }
#pragma unroll
        for (int jj = 0; jj < 2; ++jj) {
#pragma unroll
            for (int r = 0; r < 4; ++r) {
                const int t = (tcol0 + jj) * 16 + l15;
                const int dv = trow * 16 + lq * 4 + r;
                Otf[t * 36 + dv] = pov[t] * accQ[jj][r] + accO[jj][r];
            }
        }
        // ---- G: S = dtot*S + Wc K
        const float dt = dts[0];
#pragma unroll
        for (int m = 0; m < 4; ++m)
#pragma unroll
            for (int r = 0; r < 4; ++r) accS[m][r] *= dt;
#pragma unroll
        for (int kk = 0; kk < 2; ++kk) {
            short8 aw = *(const short8*)(Wcb + (trow * 16 + l15) * 72 + kk * 32 + k8o);
#pragma unroll
            for (int m = 0; m < 4; ++m) {
                short8 bk = *(const short8*)(KTb + ((scol0 + m) * 16 + l15) * 72 + kk * 32 + k8o);
                accS[m] = MFMA(aw, bk, accS[m], 0, 0, 0);
            }
        }
        __syncthreads();

        // ---- H: store O + land prefetched chunk into LDS
#pragma unroll
        for (int j = 0; j < 2; ++j) {
            const int i4 = tid + j * 256;
            const int row = i4 >> 3, c4 = i4 & 7;
            float4 ov = *(const float4*)(Otf + row * 36 + c4 * 4);
            *(float4*)(obase + (size_t)(t0 + row) * DV + c4 * 4) = ov;
        }
        if (c + 1 < NCK) WRITEC();
        __syncthreads();
    }
}

// ---------------- LayerNorm(Dv) + sigmoid gate -> bf16 ----------------
__global__ __launch_bounds__(256)
void k_ln_gate(const float* __restrict__ o, const float* __restrict__ g_lin,
               const float* __restrict__ ln_g, const float* __restrict__ ln_b,
               ushort* __restrict__ ogb)
{
    const int idx  = blockIdx.x * 4 + (threadIdx.x >> 6);
    const int lane = threadIdx.x & 63;
    const int h  = idx & 7;
    const int bt = idx >> 3;
    const int b  = bt >> 10;
    const int t  = bt & 1023;
    const float* op = o + ((size_t)(b * NH + h) * TSEQ + t) * DV;
    float2 xv = ((const float2*)op)[lane];
    float s = xv.x + xv.y;
#pragma unroll
    for (int m = 32; m; m >>= 1) s += __shfl_xor(s, m);
    const float mu = s * (1.f / 128.f);
    const float d0 = xv.x - mu, d1 = xv.y - mu;
    float v = d0 * d0 + d1 * d1;
#pragma unroll
    for (int m = 32; m; m >>= 1) v += __shfl_xor(v, m);
    const float inv = rsqrtf(v * (1.f / 128.f) + 1e-5f);
    const int d = lane * 2;
    const float* gp = g_lin + (size_t)bt * HID_ + h * DV;
    const float g0 = sig_(gp[d]), g1 = sig_(gp[d + 1]);
    const float y0 = (d0 * inv * ln_g[d]     + ln_b[d])     * g0;
    const float y1 = (d1 * inv * ln_g[d + 1] + ln_b[d + 1]) * g1;
    *(uint*)(ogb + (size_t)bt * HID_ + h * DV + d) = pk2(y0, y1);
}

extern "C" void kernel_launch(void* const* d_in, const int* in_sizes, int n_in,
                              void* d_out, int out_size, void* d_ws, size_t ws_size,
                              hipStream_t stream)
{
    const float* x   = (const float*)d_in[0];
    const float* Wq  = (const float*)d_in[1];
    const float* Wk  = (const float*)d_in[2];
    const float* Wv  = (const float*)d_in[3];
    const float* cqw = (const float*)d_in[4];
    const float* cqb = (const float*)d_in[5];
    const float* ckw = (const float*)d_in[6];
    const float* ckb = (const float*)d_in[7];
    const float* cvw = (const float*)d_in[8];
    const float* cvb = (const float*)d_in[9];
    const float* Wa  = (const float*)d_in[10];
    const float* ba  = (const float*)d_in[11];
    const float* Wb  = (const float*)d_in[12];
    const float* bb  = (const float*)d_in[13];
    const float* Wg  = (const float*)d_in[14];
    const float* Wo  = (const float*)d_in[15];
    const float* lng = (const float*)d_in[16];
    const float* lnb = (const float*)d_in[17];
    float* out = (float*)d_out;
    float* ws  = (float*)d_ws;

    float* q_lin = ws;                       // f32; dead after k_stage; ogb reuses
    float* k_lin = ws + 1 * (size_t)SZf;     // f32; dead after k_stage; WoT reuses
    float* v_lin = ws + 2 * (size_t)SZf;
    float* g_lin = ws + 3 * (size_t)SZf;
    float* o_buf = ws + 4 * (size_t)SZf;     // WT4 -> conv scratch -> scan out
    float* aT    = ws + 5 * (size_t)SZf;
    float* bT    = aT + 16 * TSEQ;
    float* pug   = bT + 16 * TSEQ;
    float* pog   = pug + 256 * 64;
    float* cgd   = pog + 256 * 64;
    float* dtg   = cgd + 256 * 64;           // 256 floats

    // new staged buffers (past the tail, 0.5MB pad)
    float*  tail = ws + 5 * (size_t)SZf + 131072;
    ushort* Kst  = (ushort*)tail;                    // 4MB
    ushort* Qst  = Kst + (size_t)256 * 8192;         // 4MB
    ushort* xbf  = Qst + (size_t)256 * 8192;         // 4MB

    ushort* WT4 = (ushort*)o_buf;            // dead after gemm4
    ushort* WoT = (ushort*)k_lin;            // written after k_stage
    ushort* ogb = (ushort*)q_lin;            // bf16 LN output (4MB)
    ushort* Mg  = (ushort*)out;              // 2MB
    ushort* Gg  = Mg + (size_t)256 * 4096;   // 2MB
    ushort* KTst = Gg + (size_t)256 * 4096;  // 4MB -> fills d_out exactly

    k_x2bf<<<1024, 256, 0, stream>>>(x, xbf);
    k_wT<<<dim3(16, 16, 4), 256, 0, stream>>>(Wq, Wk, Wv, Wg, WT4);
    k_gemm4<<<dim3(8, 16, 4), 256, 0, stream>>>(xbf, WT4, ws);
    k_ab<<<ROWS, 64, 0, stream>>>(x, Wa, ba, Wb, bb, aT, bT);
    k_conv_save<<<dim3(15, 2, 3), 256, 0, stream>>>(q_lin, k_lin, v_lin, o_buf);
    k_conv_apply<<<dim3(64, 2, 3), 256, 0, stream>>>(q_lin, k_lin, v_lin, o_buf,
                                                     cqw, cqb, ckw, ckb, cvw, cvb);
    k_stage<<<256, 256, 0, stream>>>(k_lin, q_lin, Kst, Qst, KTst);
    k_prep<<<256, 256, 0, stream>>>(Kst, Qst, aT, bT, Mg, Gg, pug, pog, cgd, dtg);
    k_wT<<<dim3(16, 16, 1), 256, 0, stream>>>(Wo, Wo, Wo, Wo, WoT);
    k_scan2<<<64, 256, 0, stream>>>(Kst, Qst, KTst, v_lin, Mg, Gg,
                                    pug, pog, cgd, dtg, o_buf);
    k_ln_gate<<<4096, 256, 0, stream>>>(o_buf, g_lin, lng, lnb, ogb);
    k_gemm1<<<dim3(8, 16), 256, 0, stream>>>(ogb, WoT, out);
}